// Round 1
// baseline (22307.620 us; speedup 1.0000x reference)
//
#include <hip/hip_runtime.h>
#include <math.h>

constexpr int B  = 32;
constexpr int NP = 196;     // num patches
constexpr int ENC = 2048;
constexpr int H  = 1024;
constexpr int VOCAB = 32000;
constexpr int ED = 512;
constexpr int S  = 32;

// ================= mean over patches + exact GELU =================
__global__ __launch_bounds__(256) void mean_gelu_kernel(const float* __restrict__ feat,
                                                        float* __restrict__ mean_enc) {
    int idx = blockIdx.x * 256 + threadIdx.x;      // b*ENC + e, total B*ENC=65536
    int b = idx >> 11;                             // /ENC
    int e = idx & (ENC - 1);
    const float* p = feat + (size_t)b * NP * ENC + e;
    float s = 0.f;
    for (int n = 0; n < NP; ++n) s += p[(size_t)n * ENC];
    s *= (1.0f / NP);
    mean_enc[idx] = 0.5f * s * (1.0f + erff(s * 0.70710678118654752440f));
}

// ================= bias sum (b_ih + b_hh) =================
__global__ void bias_sum_kernel(const float* __restrict__ a, const float* __restrict__ b,
                                float* __restrict__ o, int n) {
    int i = blockIdx.x * 256 + threadIdx.x;
    if (i < n) o[i] = a[i] + b[i];
}

// ================= embedding gather: out[(s*B+b)*ED + e] =================
__global__ __launch_bounds__(256) void gather_emb_kernel(const int* __restrict__ captions,
                                                         const float* __restrict__ emb,
                                                         float* __restrict__ out) {
    int idx = blockIdx.x * 256 + threadIdx.x;      // total S*B*ED = 524288
    int e  = idx & (ED - 1);
    int sb = idx >> 9;
    int b  = sb & (B - 1);
    int s  = sb >> 5;
    int tok = captions[b * S + s];
    out[idx] = emb[(size_t)tok * ED + e];
}

// ================= fp32 GEMM: C[M,Nn] = A[M,K] @ W[Nn,K]^T (+bias[n]) (+addmat[m,n]) ===
// BM=BN=64, BK=32, 256 threads, 4x4 register tile per thread.
__global__ __launch_bounds__(256) void gemm_tn(const float* __restrict__ A,
                                               const float* __restrict__ W,
                                               const float* __restrict__ bias,
                                               const float* __restrict__ addmat,
                                               float* __restrict__ C,
                                               int M, int Nn, int K) {
    __shared__ __align__(16) float As[32][68];
    __shared__ __align__(16) float Ws[32][68];
    const int n0 = blockIdx.x * 64;
    const int m0 = blockIdx.y * 64;
    const int t  = threadIdx.x;
    const int tr = t >> 4;       // 0..15
    const int tc = t & 15;       // 0..15
    float acc[4][4] = {};
    for (int k0 = 0; k0 < K; k0 += 32) {
#pragma unroll
        for (int i = 0; i < 8; ++i) {
            int j  = t + i * 256;          // 0..2047
            int mm = j >> 5, kk = j & 31;
            int gm = m0 + mm;
            As[kk][mm] = (gm < M) ? A[(size_t)gm * K + k0 + kk] : 0.0f;
        }
#pragma unroll
        for (int i = 0; i < 8; ++i) {
            int j  = t + i * 256;
            int nn = j >> 5, kk = j & 31;
            Ws[kk][nn] = W[(size_t)(n0 + nn) * K + k0 + kk];
        }
        __syncthreads();
#pragma unroll
        for (int k = 0; k < 32; ++k) {
            float4 a4 = *(const float4*)&As[k][tr * 4];
            float4 w4 = *(const float4*)&Ws[k][tc * 4];
            float av[4] = {a4.x, a4.y, a4.z, a4.w};
            float wv[4] = {w4.x, w4.y, w4.z, w4.w};
#pragma unroll
            for (int u = 0; u < 4; ++u)
#pragma unroll
                for (int v = 0; v < 4; ++v)
                    acc[u][v] += av[u] * wv[v];
        }
        __syncthreads();
    }
#pragma unroll
    for (int u = 0; u < 4; ++u) {
        int gm = m0 + tr * 4 + u;
        if (gm >= M) continue;
#pragma unroll
        for (int v = 0; v < 4; ++v) {
            int gn = n0 + tc * 4 + v;
            float val = acc[u][v];
            if (bias)   val += bias[gn];
            if (addmat) val += addmat[(size_t)gm * Nn + gn];
            C[(size_t)gm * Nn + gn] = val;
        }
    }
}

// ================= attention: scores + softmax + ctxv, one block per b =================
__global__ __launch_bounds__(256) void attn_kernel(const float* __restrict__ q,
                                                   const float* __restrict__ kbuf,
                                                   const float* __restrict__ vbuf,
                                                   float* __restrict__ attn_out,
                                                   float* __restrict__ ctxv, int s) {
    const int b = blockIdx.x, t = threadIdx.x;
    __shared__ float qs[H];
    __shared__ float sc[NP];
    __shared__ float red[4];
    for (int i = t; i < H; i += 256) qs[i] = q[b * H + i];
    __syncthreads();
    const int wave = t >> 6, lane = t & 63;
    for (int n = wave; n < NP; n += 4) {
        const float* kr = kbuf + ((size_t)b * NP + n) * H;
        float acc = 0.f;
        for (int i = lane; i < H; i += 64) acc += qs[i] * kr[i];
#pragma unroll
        for (int o = 32; o > 0; o >>= 1) acc += __shfl_down(acc, o, 64);
        if (lane == 0) sc[n] = acc * (1.0f / 32.0f);
    }
    __syncthreads();
    // softmax over NP
    float m = -1e30f;
    for (int n = t; n < NP; n += 256) m = fmaxf(m, sc[n]);
#pragma unroll
    for (int o = 32; o > 0; o >>= 1) m = fmaxf(m, __shfl_down(m, o, 64));
    if (lane == 0) red[wave] = m;
    __syncthreads();
    m = fmaxf(fmaxf(red[0], red[1]), fmaxf(red[2], red[3]));
    __syncthreads();
    float ssum = 0.f;
    for (int n = t; n < NP; n += 256) { float e = expf(sc[n] - m); sc[n] = e; ssum += e; }
#pragma unroll
    for (int o = 32; o > 0; o >>= 1) ssum += __shfl_down(ssum, o, 64);
    if (lane == 0) red[wave] = ssum;
    __syncthreads();
    ssum = red[0] + red[1] + red[2] + red[3];
    const float inv = 1.0f / ssum;
    __syncthreads();
    for (int n = t; n < NP; n += 256) sc[n] *= inv;
    __syncthreads();
    for (int n = t; n < NP; n += 256)
        attn_out[((size_t)b * S + s) * NP + n] = sc[n];
    // ctxv[b,h] = sum_n sc[n]*v[b,n,h]
    for (int h = t; h < H; h += 256) {
        const float* vb = vbuf + (size_t)b * NP * H + h;
        float acc = 0.f;
        for (int n = 0; n < NP; ++n) acc += sc[n] * vb[(size_t)n * H];
        ctxv[b * H + h] = acc;
    }
}

// ================= LayerNorm(h_prev + ctx) =================
__global__ __launch_bounds__(256) void ln_kernel(const float* __restrict__ hprev,
                                                 const float* __restrict__ ctx,
                                                 const float* __restrict__ g,
                                                 const float* __restrict__ beta,
                                                 float* __restrict__ hln) {
    const int b = blockIdx.x, t = threadIdx.x;
    __shared__ float red[4];
    float x[4];
    float s = 0.f;
#pragma unroll
    for (int j = 0; j < 4; ++j) {
        int i = t + j * 256;
        x[j] = hprev[b * H + i] + ctx[b * H + i];
        s += x[j];
    }
#pragma unroll
    for (int o = 32; o > 0; o >>= 1) s += __shfl_down(s, o, 64);
    if ((t & 63) == 0) red[t >> 6] = s;
    __syncthreads();
    float mu = (red[0] + red[1] + red[2] + red[3]) * (1.0f / H);
    __syncthreads();
    float vs = 0.f;
#pragma unroll
    for (int j = 0; j < 4; ++j) { float d = x[j] - mu; vs += d * d; }
#pragma unroll
    for (int o = 32; o > 0; o >>= 1) vs += __shfl_down(vs, o, 64);
    if ((t & 63) == 0) red[t >> 6] = vs;
    __syncthreads();
    float rstd = rsqrtf((red[0] + red[1] + red[2] + red[3]) * (1.0f / H) + 1e-5f);
#pragma unroll
    for (int j = 0; j < 4; ++j) {
        int i = t + j * 256;
        hln[b * H + i] = (x[j] - mu) * rstd * g[i] + beta[i];
    }
}

// ================= LSTM cell =================
__global__ __launch_bounds__(256) void lstm_cell_kernel(const float* __restrict__ gates,
                                                        float* __restrict__ h,
                                                        float* __restrict__ c,
                                                        float* __restrict__ Hall, int s) {
    int idx = blockIdx.x * 256 + threadIdx.x;   // b*H + i, total B*H
    int b = idx >> 10, i = idx & (H - 1);
    const float* gr = gates + (size_t)b * 4 * H;
    float ig = gr[i], fg = gr[H + i], gg = gr[2 * H + i], og = gr[3 * H + i];
    float si = 1.f / (1.f + expf(-ig));
    float sf = 1.f / (1.f + expf(-fg));
    float so = 1.f / (1.f + expf(-og));
    float cn = sf * c[idx] + si * tanhf(gg);
    float hn = so * tanhf(cn);
    c[idx] = cn;
    h[idx] = hn;
    Hall[((size_t)b * S + s) * H + i] = hn;
}

// ================= launch =================
extern "C" void kernel_launch(void* const* d_in, const int* in_sizes, int n_in,
                              void* d_out, int out_size, void* d_ws, size_t ws_size,
                              hipStream_t stream) {
    const float* features = (const float*)d_in[0];
    const int*   captions = (const int*)d_in[1];
    const float* emb      = (const float*)d_in[2];
    const float* q_w      = (const float*)d_in[3];
    const float* k_w      = (const float*)d_in[4];
    const float* v_w      = (const float*)d_in[5];
    const float* in_b     = (const float*)d_in[6];
    const float* out_w    = (const float*)d_in[7];
    const float* out_b    = (const float*)d_in[8];
    const float* h0_w     = (const float*)d_in[9];
    const float* h0_b     = (const float*)d_in[10];
    const float* c0_w     = (const float*)d_in[11];
    const float* c0_b     = (const float*)d_in[12];
    const float* w_ih     = (const float*)d_in[13];
    const float* b_ih     = (const float*)d_in[14];
    const float* w_hh     = (const float*)d_in[15];
    const float* b_hh     = (const float*)d_in[16];
    const float* ln_g     = (const float*)d_in[17];
    const float* ln_b2    = (const float*)d_in[18];
    const float* lin_w    = (const float*)d_in[19];
    const float* lin_b    = (const float*)d_in[20];

    float* out = (float*)d_out;
    float* preds    = out;                                   // [B,S,VOCAB]
    float* attn_out = out + (size_t)B * S * VOCAB;           // [B,S,NP]

    float* ws = (float*)d_ws;
    float* mean_enc = ws;                         // 65536
    float* h_cur = mean_enc + (size_t)B * ENC;    // 32768
    float* c_cur = h_cur + (size_t)B * H;         // 32768
    float* kbuf  = c_cur + (size_t)B * H;         // 6422528
    float* vbuf  = kbuf + (size_t)B * NP * H;     // 6422528
    float* embeds = vbuf + (size_t)B * NP * H;    // 524288  [(s*B+b), ED]
    float* xg    = embeds + (size_t)S * B * ED;   // 4194304 [(s*B+b), 4H]
    float* bias2 = xg + (size_t)S * B * 4 * H;    // 4096
    float* qbuf  = bias2 + 4 * H;                 // 32768
    float* ctxv  = qbuf + (size_t)B * H;          // 32768
    float* ctxb  = ctxv + (size_t)B * H;          // 32768
    float* hln   = ctxb + (size_t)B * H;          // 32768
    float* gates = hln + (size_t)B * H;           // 131072
    float* Hall  = gates + (size_t)B * 4 * H;     // 1048576 [(b*S+s), H]

    // ---- setup (hoisted out of scan) ----
    mean_gelu_kernel<<<(B * ENC) / 256, 256, 0, stream>>>(features, mean_enc);
    bias_sum_kernel<<<(4 * H) / 256, 256, 0, stream>>>(b_ih, b_hh, bias2, 4 * H);
    gather_emb_kernel<<<(S * B * ED) / 256, 256, 0, stream>>>(captions, emb, embeds);

    // h0, c0: [32,2048]@[1024,2048]^T
    gemm_tn<<<dim3(H / 64, 1), 256, 0, stream>>>(mean_enc, h0_w, h0_b, nullptr, h_cur, B, H, ENC);
    gemm_tn<<<dim3(H / 64, 1), 256, 0, stream>>>(mean_enc, c0_w, c0_b, nullptr, c_cur, B, H, ENC);
    // k, v: [6272,2048]@[1024,2048]^T
    gemm_tn<<<dim3(H / 64, (B * NP) / 64), 256, 0, stream>>>(features, k_w, in_b + H,     nullptr, kbuf, B * NP, H, ENC);
    gemm_tn<<<dim3(H / 64, (B * NP) / 64), 256, 0, stream>>>(features, v_w, in_b + 2 * H, nullptr, vbuf, B * NP, H, ENC);
    // x gates for all steps: [1024,512]@[4096,512]^T + (b_ih+b_hh)
    gemm_tn<<<dim3((4 * H) / 64, (S * B) / 64), 256, 0, stream>>>(embeds, w_ih, bias2, nullptr, xg, S * B, 4 * H, ED);

    // ---- sequential scan ----
    for (int s = 0; s < S; ++s) {
        // q = h @ q_w^T + in_b[:H]
        gemm_tn<<<dim3(H / 64, 1), 256, 0, stream>>>(h_cur, q_w, in_b, nullptr, qbuf, B, H, H);
        // attention + softmax + ctxv; writes attn slice of output
        attn_kernel<<<B, 256, 0, stream>>>(qbuf, kbuf, vbuf, attn_out, ctxv, s);
        // ctx = ctxv @ out_w^T + out_b
        gemm_tn<<<dim3(H / 64, 1), 256, 0, stream>>>(ctxv, out_w, out_b, nullptr, ctxb, B, H, H);
        // h_ln = LN(h + ctx)
        ln_kernel<<<B, 256, 0, stream>>>(h_cur, ctxb, ln_g, ln_b2, hln);
        // gates = xg[s] + h_ln @ w_hh^T
        gemm_tn<<<dim3((4 * H) / 64, 1), 256, 0, stream>>>(hln, w_hh, nullptr,
                                                           xg + (size_t)s * B * 4 * H, gates, B, 4 * H, H);
        // LSTM cell; writes h into Hall[(b*S+s)]
        lstm_cell_kernel<<<(B * H) / 256, 256, 0, stream>>>(gates, h_cur, c_cur, Hall, s);
    }

    // ---- deferred vocab projection: [1024,1024]@[32000,1024]^T + lin_b -> preds ----
    gemm_tn<<<dim3(VOCAB / 64, (B * S) / 64), 256, 0, stream>>>(Hall, lin_w, lin_b, nullptr, preds, B * S, VOCAB, H);
}

// Round 2
// 9453.909 us; speedup vs baseline: 2.3596x; 2.3596x over previous
//
#include <hip/hip_runtime.h>
#include <math.h>

constexpr int B  = 32;
constexpr int NP = 196;     // num patches
constexpr int ENC = 2048;
constexpr int H  = 1024;
constexpr int VOCAB = 32000;
constexpr int ED = 512;
constexpr int S  = 32;
constexpr int GRID = 256;   // persistent kernel blocks (must all be co-resident)
constexpr int TPB  = 512;   // 8 waves

// ================= mean over patches + exact GELU =================
__global__ __launch_bounds__(256) void mean_gelu_kernel(const float* __restrict__ feat,
                                                        float* __restrict__ mean_enc) {
    int idx = blockIdx.x * 256 + threadIdx.x;      // b*ENC + e, total B*ENC=65536
    int b = idx >> 11;                             // /ENC
    int e = idx & (ENC - 1);
    const float* p = feat + (size_t)b * NP * ENC + e;
    float s = 0.f;
    for (int n = 0; n < NP; ++n) s += p[(size_t)n * ENC];
    s *= (1.0f / NP);
    mean_enc[idx] = 0.5f * s * (1.0f + erff(s * 0.70710678118654752440f));
}

// ================= bias sum (b_ih + b_hh) =================
__global__ void bias_sum_kernel(const float* __restrict__ a, const float* __restrict__ b,
                                float* __restrict__ o, int n) {
    int i = blockIdx.x * 256 + threadIdx.x;
    if (i < n) o[i] = a[i] + b[i];
}

// ================= zero the barrier flags =================
__global__ void zero_flags_kernel(int* __restrict__ flags) {
    flags[threadIdx.x] = 0;
}

// ================= embedding gather: out[(s*B+b)*ED + e] =================
__global__ __launch_bounds__(256) void gather_emb_kernel(const int* __restrict__ captions,
                                                         const float* __restrict__ emb,
                                                         float* __restrict__ out) {
    int idx = blockIdx.x * 256 + threadIdx.x;      // total S*B*ED = 524288
    int e  = idx & (ED - 1);
    int sb = idx >> 9;
    int b  = sb & (B - 1);
    int s  = sb >> 5;
    int tok = captions[b * S + s];
    out[idx] = emb[(size_t)tok * ED + e];
}

// ================= fp32 GEMM: C[M,Nn] = A[M,K] @ W[Nn,K]^T (+bias[n]) ===
// BM=BN=64, BK=32, 256 threads, 4x4 register tile per thread.
__global__ __launch_bounds__(256) void gemm_tn(const float* __restrict__ A,
                                               const float* __restrict__ W,
                                               const float* __restrict__ bias,
                                               const float* __restrict__ addmat,
                                               float* __restrict__ C,
                                               int M, int Nn, int K) {
    __shared__ __align__(16) float As[32][68];
    __shared__ __align__(16) float Ws[32][68];
    const int n0 = blockIdx.x * 64;
    const int m0 = blockIdx.y * 64;
    const int t  = threadIdx.x;
    const int tr = t >> 4;       // 0..15
    const int tc = t & 15;       // 0..15
    float acc[4][4] = {};
    for (int k0 = 0; k0 < K; k0 += 32) {
#pragma unroll
        for (int i = 0; i < 8; ++i) {
            int j  = t + i * 256;          // 0..2047
            int mm = j >> 5, kk = j & 31;
            int gm = m0 + mm;
            As[kk][mm] = (gm < M) ? A[(size_t)gm * K + k0 + kk] : 0.0f;
        }
#pragma unroll
        for (int i = 0; i < 8; ++i) {
            int j  = t + i * 256;
            int nn = j >> 5, kk = j & 31;
            Ws[kk][nn] = W[(size_t)(n0 + nn) * K + k0 + kk];
        }
        __syncthreads();
#pragma unroll
        for (int k = 0; k < 32; ++k) {
            float4 a4 = *(const float4*)&As[k][tr * 4];
            float4 w4 = *(const float4*)&Ws[k][tc * 4];
            float av[4] = {a4.x, a4.y, a4.z, a4.w};
            float wv[4] = {w4.x, w4.y, w4.z, w4.w};
#pragma unroll
            for (int u = 0; u < 4; ++u)
#pragma unroll
                for (int v = 0; v < 4; ++v)
                    acc[u][v] += av[u] * wv[v];
        }
        __syncthreads();
    }
#pragma unroll
    for (int u = 0; u < 4; ++u) {
        int gm = m0 + tr * 4 + u;
        if (gm >= M) continue;
#pragma unroll
        for (int v = 0; v < 4; ++v) {
            int gn = n0 + tc * 4 + v;
            float val = acc[u][v];
            if (bias)   val += bias[gn];
            if (addmat) val += addmat[(size_t)gm * Nn + gn];
            C[(size_t)gm * Nn + gn] = val;
        }
    }
}

// ================= persistent scan kernel helpers =================
__device__ __forceinline__ float wred_sum(float v) {
#pragma unroll
    for (int o = 32; o > 0; o >>= 1) v += __shfl_down(v, o, 64);
    return v;  // lane 0 holds the sum
}

// grid barrier: flag-array, store-release / load-acquire at agent scope
__device__ __forceinline__ void gbar(int* __restrict__ flags, int g, int t, int ep) {
    __syncthreads();
    if (t == 0)
        __hip_atomic_store(&flags[g], ep, __ATOMIC_RELEASE, __HIP_MEMORY_SCOPE_AGENT);
    if (t < GRID) {
        while (__hip_atomic_load(&flags[t], __ATOMIC_ACQUIRE, __HIP_MEMORY_SCOPE_AGENT) < ep)
            __builtin_amdgcn_s_sleep(2);
    }
    __syncthreads();
}

// 32x1024 projection: C[b,j] = dot(A[b,:], W[j,:]) + bias[j]
// block tile: 4 b's (g>>5) x 32 j's (g&31); wave handles 4 j x 4 b
__device__ __forceinline__ void proj_phase(const float* __restrict__ A,
                                           const float* __restrict__ W,
                                           const float* __restrict__ bias,
                                           float* __restrict__ C,
                                           int g, int wave, int lane) {
    const int jblk = g & 31, bgrp = g >> 5;
#pragma unroll 1
    for (int bb = 0; bb < 4; ++bb) {
        const int b = bgrp * 4 + bb;
        float4 ha[4];
#pragma unroll
        for (int u = 0; u < 4; ++u)
            ha[u] = *(const float4*)&A[b * H + u * 256 + lane * 4];
#pragma unroll 1
        for (int jj = 0; jj < 4; ++jj) {
            const int j = jblk * 32 + wave * 4 + jj;
            const float* wr = &W[j * H];
            float acc = 0.f;
#pragma unroll
            for (int u = 0; u < 4; ++u) {
                float4 wv = *(const float4*)&wr[u * 256 + lane * 4];
                acc += ha[u].x * wv.x + ha[u].y * wv.y + ha[u].z * wv.z + ha[u].w * wv.w;
            }
            acc = wred_sum(acc);
            if (lane == 0) C[b * H + j] = acc + bias[j];
        }
    }
}

// ================= the persistent scan kernel =================
__global__ __launch_bounds__(TPB) void scan_kernel(
    const float* __restrict__ q_w, const float* __restrict__ out_w,
    const float* __restrict__ w_hh,
    const float* __restrict__ in_b, const float* __restrict__ out_b,
    const float* __restrict__ ln_g, const float* __restrict__ ln_b2,
    const float* __restrict__ xg, const float* __restrict__ kbuf,
    const float* __restrict__ vbuf,
    float* __restrict__ h, float* __restrict__ c, float* __restrict__ Hall,
    float* __restrict__ qg, float* __restrict__ scg,
    float* __restrict__ ctxv, float* __restrict__ ctxb,
    float* __restrict__ attn_out, int* __restrict__ flags)
{
    const int g = blockIdx.x, t = threadIdx.x;
    const int wave = t >> 6, lane = t & 63;
    __shared__ __align__(16) float hln[4][H];        // 16 KB
    __shared__ float sarr[NP + 12];
    __shared__ float redA[4][8], redB[4][8], muv[4], rsv[4], mls[2];
    int ep = 0;

    for (int s = 0; s < S; ++s) {
        // ---- phase Q: q = h @ q_w^T + in_b[:H] ----
        proj_phase(h, q_w, in_b, qg, g, wave, lane);
        gbar(flags, g, t, ++ep);

        // ---- phase S: scores(b,n) = dot(q[b], k[b,n]) / 32 ----
        for (int job = g * 8 + wave; job < B * NP; job += GRID * 8) {
            const int b = job / NP;
            const int n = job - b * NP;
            const float* qr = &qg[b * H];
            const float* kr = &kbuf[(b * NP + n) * H];
            float acc = 0.f;
#pragma unroll
            for (int u = 0; u < 4; ++u) {
                float4 a4 = *(const float4*)&qr[u * 256 + lane * 4];
                float4 k4 = *(const float4*)&kr[u * 256 + lane * 4];
                acc += a4.x * k4.x + a4.y * k4.y + a4.z * k4.z + a4.w * k4.w;
            }
            acc = wred_sum(acc);
            if (lane == 0) scg[job] = acc * (1.0f / 32.0f);
        }
        gbar(flags, g, t, ++ep);

        // ---- phase SM+CTX: softmax (redundant per block) + ctxv ----
        {
            const int b = g >> 3, hblk = g & 7;
            for (int n = t; n < NP; n += TPB) sarr[n] = scg[b * NP + n];
            __syncthreads();
            if (wave == 0) {
                float m = -1e30f;
                for (int n = lane; n < NP; n += 64) m = fmaxf(m, sarr[n]);
#pragma unroll
                for (int o = 32; o > 0; o >>= 1) m = fmaxf(m, __shfl_down(m, o, 64));
                m = __shfl(m, 0, 64);
                float l = 0.f;
                for (int n = lane; n < NP; n += 64) l += expf(sarr[n] - m);
                l = wred_sum(l);
                if (lane == 0) { mls[0] = m; mls[1] = 1.0f / l; }
            }
            __syncthreads();
            const float m = mls[0], inv = mls[1];
            for (int n = t; n < NP; n += TPB) {
                float p = expf(sarr[n] - m) * inv;
                sarr[n] = p;
                if (hblk == 0) attn_out[(b * S + s) * NP + n] = p;
            }
            __syncthreads();
            if (wave < 2) {
                const int hcol = hblk * 128 + wave * 64 + lane;
                const float* vb = &vbuf[b * NP * H + hcol];
                float acc = 0.f;
#pragma unroll 4
                for (int n = 0; n < NP; ++n) acc += sarr[n] * vb[n * H];
                ctxv[b * H + hcol] = acc;
            }
        }
        gbar(flags, g, t, ++ep);

        // ---- phase O: ctxb = ctxv @ out_w^T + out_b ----
        proj_phase(ctxv, out_w, out_b, ctxb, g, wave, lane);
        gbar(flags, g, t, ++ep);

        // ---- phase LN (redundant per block, into LDS) + gates + cell ----
        {
            const int bgrp = g >> 5, iblk = g & 31;
#pragma unroll 1
            for (int bb = 0; bb < 4; ++bb) {
                const int b = bgrp * 4 + bb;
                const float x0 = h[b * H + t] + ctxb[b * H + t];
                const float x1 = h[b * H + t + 512] + ctxb[b * H + t + 512];
                float ssum = x0 + x1, s2 = x0 * x0 + x1 * x1;
                ssum = wred_sum(ssum); s2 = wred_sum(s2);
                if (lane == 0) { redA[bb][wave] = ssum; redB[bb][wave] = s2; }
                __syncthreads();
                if (t == 0) {
                    float sa = 0.f, sb = 0.f;
                    for (int w = 0; w < 8; ++w) { sa += redA[bb][w]; sb += redB[bb][w]; }
                    const float mu = sa * (1.0f / H);
                    const float var = fmaxf(sb * (1.0f / H) - mu * mu, 0.0f);
                    muv[bb] = mu; rsv[bb] = rsqrtf(var + 1e-5f);
                }
                __syncthreads();
                const float mu = muv[bb], rs = rsv[bb];
                hln[bb][t]       = (x0 - mu) * rs * ln_g[t] + ln_b2[t];
                hln[bb][t + 512] = (x1 - mu) * rs * ln_g[t + 512] + ln_b2[t + 512];
            }
            __syncthreads();
#pragma unroll 1
            for (int bb = 0; bb < 4; ++bb) {
                const int b = bgrp * 4 + bb;
                float4 hs[4];
#pragma unroll
                for (int u = 0; u < 4; ++u)
                    hs[u] = *(const float4*)&hln[bb][u * 256 + lane * 4];
#pragma unroll 1
                for (int ii = 0; ii < 4; ++ii) {
                    const int i = iblk * 32 + wave * 4 + ii;
                    float a0 = 0.f, a1 = 0.f, a2 = 0.f, a3 = 0.f;
#pragma unroll
                    for (int u = 0; u < 4; ++u) {
                        const int ko = u * 256 + lane * 4;
                        float4 w0 = *(const float4*)&w_hh[(size_t)(i) * H + ko];
                        float4 w1 = *(const float4*)&w_hh[(size_t)(H + i) * H + ko];
                        float4 w2 = *(const float4*)&w_hh[(size_t)(2 * H + i) * H + ko];
                        float4 w3 = *(const float4*)&w_hh[(size_t)(3 * H + i) * H + ko];
                        a0 += hs[u].x * w0.x + hs[u].y * w0.y + hs[u].z * w0.z + hs[u].w * w0.w;
                        a1 += hs[u].x * w1.x + hs[u].y * w1.y + hs[u].z * w1.z + hs[u].w * w1.w;
                        a2 += hs[u].x * w2.x + hs[u].y * w2.y + hs[u].z * w2.z + hs[u].w * w2.w;
                        a3 += hs[u].x * w3.x + hs[u].y * w3.y + hs[u].z * w3.z + hs[u].w * w3.w;
                    }
                    a0 = wred_sum(a0); a1 = wred_sum(a1); a2 = wred_sum(a2); a3 = wred_sum(a3);
                    if (lane == 0) {
                        const float* xr = &xg[(size_t)(s * B + b) * 4 * H];
                        const float gi = a0 + xr[i];
                        const float gf = a1 + xr[H + i];
                        const float gg_ = a2 + xr[2 * H + i];
                        const float go = a3 + xr[3 * H + i];
                        const float si = 1.f / (1.f + expf(-gi));
                        const float sf = 1.f / (1.f + expf(-gf));
                        const float so = 1.f / (1.f + expf(-go));
                        const float cn = sf * c[b * H + i] + si * tanhf(gg_);
                        const float hn = so * tanhf(cn);
                        c[b * H + i] = cn;
                        h[b * H + i] = hn;
                        Hall[(b * S + s) * H + i] = hn;
                    }
                }
            }
        }
        gbar(flags, g, t, ++ep);  // h/c ready for next step
    }
}

// ================= launch =================
extern "C" void kernel_launch(void* const* d_in, const int* in_sizes, int n_in,
                              void* d_out, int out_size, void* d_ws, size_t ws_size,
                              hipStream_t stream) {
    const float* features = (const float*)d_in[0];
    const int*   captions = (const int*)d_in[1];
    const float* emb      = (const float*)d_in[2];
    const float* q_w      = (const float*)d_in[3];
    const float* k_w      = (const float*)d_in[4];
    const float* v_w      = (const float*)d_in[5];
    const float* in_b     = (const float*)d_in[6];
    const float* out_w    = (const float*)d_in[7];
    const float* out_b    = (const float*)d_in[8];
    const float* h0_w     = (const float*)d_in[9];
    const float* h0_b     = (const float*)d_in[10];
    const float* c0_w     = (const float*)d_in[11];
    const float* c0_b     = (const float*)d_in[12];
    const float* w_ih     = (const float*)d_in[13];
    const float* b_ih     = (const float*)d_in[14];
    const float* w_hh     = (const float*)d_in[15];
    const float* b_hh     = (const float*)d_in[16];
    const float* ln_g     = (const float*)d_in[17];
    const float* ln_b2    = (const float*)d_in[18];
    const float* lin_w    = (const float*)d_in[19];
    const float* lin_b    = (const float*)d_in[20];

    float* out = (float*)d_out;
    float* preds    = out;                                   // [B,S,VOCAB]
    float* attn_out = out + (size_t)B * S * VOCAB;           // [B,S,NP]

    float* ws = (float*)d_ws;
    float* mean_enc = ws;                         // 65536
    float* h_cur = mean_enc + (size_t)B * ENC;    // 32768
    float* c_cur = h_cur + (size_t)B * H;         // 32768
    float* kbuf  = c_cur + (size_t)B * H;         // 6422528
    float* vbuf  = kbuf + (size_t)B * NP * H;     // 6422528
    float* embeds = vbuf + (size_t)B * NP * H;    // 524288  [(s*B+b), ED]
    float* xg    = embeds + (size_t)S * B * ED;   // 4194304 [(s*B+b), 4H]
    float* bias2 = xg + (size_t)S * B * 4 * H;    // 4096
    float* qg    = bias2 + 4 * H;                 // 32768
    float* ctxv  = qg + (size_t)B * H;            // 32768
    float* ctxb  = ctxv + (size_t)B * H;          // 32768
    float* Hall  = ctxb + (size_t)B * H;          // 1048576 [(b*S+s), H]
    float* scg   = Hall + (size_t)B * S * H;      // 6272
    int*   flags = (int*)(scg + B * NP);          // 256

    // ---- setup (hoisted out of scan) ----
    zero_flags_kernel<<<1, GRID, 0, stream>>>(flags);
    mean_gelu_kernel<<<(B * ENC) / 256, 256, 0, stream>>>(features, mean_enc);
    bias_sum_kernel<<<(4 * H) / 256, 256, 0, stream>>>(b_ih, b_hh, bias2, 4 * H);
    gather_emb_kernel<<<(S * B * ED) / 256, 256, 0, stream>>>(captions, emb, embeds);

    // h0, c0: [32,2048]@[1024,2048]^T
    gemm_tn<<<dim3(H / 64, 1), 256, 0, stream>>>(mean_enc, h0_w, h0_b, nullptr, h_cur, B, H, ENC);
    gemm_tn<<<dim3(H / 64, 1), 256, 0, stream>>>(mean_enc, c0_w, c0_b, nullptr, c_cur, B, H, ENC);
    // k, v: [6272,2048]@[1024,2048]^T
    gemm_tn<<<dim3(H / 64, (B * NP) / 64), 256, 0, stream>>>(features, k_w, in_b + H,     nullptr, kbuf, B * NP, H, ENC);
    gemm_tn<<<dim3(H / 64, (B * NP) / 64), 256, 0, stream>>>(features, v_w, in_b + 2 * H, nullptr, vbuf, B * NP, H, ENC);
    // x gates for all steps: [1024,512]@[4096,512]^T + (b_ih+b_hh)
    gemm_tn<<<dim3((4 * H) / 64, (S * B) / 64), 256, 0, stream>>>(embeds, w_ih, bias2, nullptr, xg, S * B, 4 * H, ED);

    // ---- the whole sequential scan in ONE persistent kernel ----
    scan_kernel<<<GRID, TPB, 0, stream>>>(q_w, out_w, w_hh, in_b, out_b, ln_g, ln_b2,
                                          xg, kbuf, vbuf, h_cur, c_cur, Hall,
                                          qg, scg, ctxv, ctxb, attn_out, flags);

    // ---- deferred vocab projection: [1024,1024]@[32000,1024]^T + lin_b -> preds ----
    gemm_tn<<<dim3(VOCAB / 64, (B * S) / 64), 256, 0, stream>>>(Hall, lin_w, lin_b, nullptr, preds, B * S, VOCAB, H);
}